// Round 6
// baseline (310.466 us; speedup 1.0000x reference)
//
#include <hip/hip_runtime.h>

#define HW 128

typedef __attribute__((ext_vector_type(8))) short  bfrag;   // 8 bf16 (4 VGPRs)
typedef __attribute__((ext_vector_type(16))) float f16x;    // 32x32 accumulator

__device__ __forceinline__ float lrelu(float x) { return x > 0.f ? x : 0.1f * x; }

// RNE fp32 -> bf16 (prep only)
__device__ __forceinline__ short f2bf(float f) {
    unsigned u = __builtin_bit_cast(unsigned, f);
    u = u + 0x7FFFu + ((u >> 16) & 1u);
    return (short)(u >> 16);
}
__device__ __forceinline__ float bf2f(short s) {
    return __builtin_bit_cast(float, (unsigned)(unsigned short)s << 16);
}

__device__ float g_kern[32 * 768];                // [b][c][12] att-folded taps (9 used)
__device__ short g_whi[4096], g_wlo[4096];        // conv_w bf16 hi/lo, [o*64+c]

// ---------- prep: b<32 -> att-folded kernels; b==32 -> W hi/lo split ----------
__global__ __launch_bounds__(64) void dgfem_prep(
    const float* __restrict__ v, const float* __restrict__ ca_w1,
    const float* __restrict__ ca_w2, const float* __restrict__ k_w1,
    const float* __restrict__ k_w2, const float* __restrict__ conv_w)
{
    const int b = blockIdx.x;
    const int t = threadIdx.x;           // 64 threads

    if (b == 32) {                       // bf16 hi/lo decomposition of conv_w
        for (int i = t; i < 4096; i += 64) {
            float wv = conv_w[i];
            short hi = f2bf(wv);
            short lo = f2bf(wv - bf2f(hi));
            g_whi[i] = hi;
            g_wlo[i] = lo;
        }
        return;
    }

    __shared__ float vb[64], t1[8], att[64], t2[64];
    vb[t] = v[b * 64 + t];
    __syncthreads();

    if (t < 8) {
        float s = 0.f;
        for (int j = 0; j < 64; ++j) s += vb[j] * ca_w1[t * 64 + j];
        t1[t] = lrelu(s);
    }
    {
        float s = 0.f;
        for (int j = 0; j < 64; ++j) s += vb[j] * k_w1[t * 64 + j];
        t2[t] = lrelu(s);
    }
    __syncthreads();
    {
        float s = 0.f;
        for (int i = 0; i < 8; ++i) s += t1[i] * ca_w2[t * 8 + i];
        att[t] = 1.f / (1.f + expf(-s));
    }
    __syncthreads();
    // fold att[c] into kernel (conv(x*a,k) == conv(x,a*k)); stride-12 rows
    for (int r = t; r < 576; r += 64) {
        int c = r / 9, tp = r - c * 9;
        float s = 0.f;
        for (int j = 0; j < 64; ++j) s += t2[j] * k_w2[r * 64 + j];
        g_kern[b * 768 + c * 12 + tp] = s * att[c];
    }
}

// ---- fused: vectorized depthwise 3x3 -> LDS (bf16 hi/lo) -> MFMA 1x1 + bias ----
__global__ __launch_bounds__(256, 4) void dgfem_main(
    const float* __restrict__ x0, const float* __restrict__ conv_b,
    float* __restrict__ out)
{
    const int t = threadIdx.x;

    // XCD-aware swizzle: XCD k gets contiguous (b,gy) rows
    const int bid  = blockIdx.x;                 // 0..4095
    const int orig = (bid & 7) * 512 + (bid >> 3);
    const int b    = orig >> 7;                  // 0..31
    const int gy   = orig & 127;                 // output row

    __shared__ __align__(16) float kls[768];     // this b's taps [c][12]
    __shared__ __align__(16) short yhi[8192];    // [px][64] bf16 hi, chunk-swizzled
    __shared__ __align__(16) short ylo[8192];    // [px][64] bf16 lo

    for (int i = t; i < 768; i += 256) kls[i] = g_kern[b * 768 + i];
    __syncthreads();

    // ---------------- phase 1: y = lrelu(dwconv(x)) for 4 px x 8 ch ----------------
    const int pxg = t & 31;                      // px group: px0 = 4*pxg (16B aligned)
    const int cg  = t >> 5;                      // channel group: c = 8*cg + j
    const int px0 = pxg << 2;

    const float mL = (pxg == 0) ? 0.f : 1.f;
    const float mR = (pxg == 31) ? 0.f : 1.f;
    const int offL = (pxg == 0) ? 0 : (px0 - 1);
    const int offR = (pxg == 31) ? 127 : (px0 + 4);

    float myv[3]; int cyv[3];
    #pragma unroll
    for (int dy = 0; dy < 3; ++dy) {
        int yi = gy + dy - 1;
        bool in = (unsigned)yi < HW;
        myv[dy] = in ? 1.f : 0.f;
        cyv[dy] = in ? yi : 0;
    }

    const float* xbase = x0 + ((size_t)b << 20);
    float yv[8][4];

    #pragma unroll
    for (int j = 0; j < 8; ++j) {
        const int c = (cg << 3) + j;
        const float4* kq = (const float4*)&kls[c * 12];
        float4 q0 = kq[0], q1 = kq[1], q2 = kq[2];
        const float* xc = xbase + (c << 14);
        float a0 = 0.f, a1 = 0.f, a2 = 0.f, a3 = 0.f;
        #pragma unroll
        for (int dy = 0; dy < 3; ++dy) {
            const float* row = xc + cyv[dy] * HW;
            float4 Q = *(const float4*)(row + px0);
            float  L = row[offL] * mL;
            float  R = row[offR] * mR;
            float k0, k1, k2;
            if (dy == 0)      { k0 = q0.x; k1 = q0.y; k2 = q0.z; }
            else if (dy == 1) { k0 = q0.w; k1 = q1.x; k2 = q1.y; }
            else              { k0 = q1.z; k1 = q1.w; k2 = q2.x; }
            k0 *= myv[dy]; k1 *= myv[dy]; k2 *= myv[dy];
            a0 = fmaf(k0, L,   fmaf(k1, Q.x, fmaf(k2, Q.y, a0)));
            a1 = fmaf(k0, Q.x, fmaf(k1, Q.y, fmaf(k2, Q.z, a1)));
            a2 = fmaf(k0, Q.y, fmaf(k1, Q.z, fmaf(k2, Q.w, a2)));
            a3 = fmaf(k0, Q.z, fmaf(k1, Q.w, fmaf(k2, R,   a3)));
        }
        yv[j][0] = lrelu(a0); yv[j][1] = lrelu(a1);
        yv[j][2] = lrelu(a2); yv[j][3] = lrelu(a3);
    }

    // truncation hi/lo split (hi+lo == y exactly to bf16-pair precision) -> LDS
    #pragma unroll
    for (int r = 0; r < 4; ++r) {
        const int px = px0 + r;
        const int chunk = cg ^ (px & 7) ^ ((px >> 2) & 7);   // both-sides conflict-free
        bfrag hv, lv;
        #pragma unroll
        for (int j = 0; j < 8; ++j) {
            float y = yv[j][r];
            unsigned u = __builtin_bit_cast(unsigned, y);
            float hif = __builtin_bit_cast(float, u & 0xFFFF0000u);
            float lof = y - hif;                 // exact residual
            hv[j] = (short)(u >> 16);
            lv[j] = (short)(__builtin_bit_cast(unsigned, lof) >> 16);
        }
        *(bfrag*)&yhi[px * 64 + chunk * 8] = hv;
        *(bfrag*)&ylo[px * 64 + chunk * 8] = lv;
    }
    __syncthreads();

    // ---------------- phase 2: out[o][px] = W[o][c] . y[c][px] via MFMA ----------------
    const int wv = t >> 6;                       // wave = px n-tile
    const int l  = t & 63;
    const int g  = l >> 5;                       // k-half
    const int ln = l & 31;                       // col / A-row
    const int px = (wv << 5) + ln;

    f16x acc0, acc1;
    #pragma unroll
    for (int i = 0; i < 16; ++i) { acc0[i] = 0.f; acc1[i] = 0.f; }

    const int woffb = ln * 128 + g * 16;         // byte offset into W rows

    #pragma unroll
    for (int s = 0; s < 4; ++s) {
        const int chunk = ((s << 1) + g) ^ (px & 7) ^ ((px >> 2) & 7);
        bfrag yh = *(const bfrag*)&yhi[px * 64 + chunk * 8];
        bfrag yl = *(const bfrag*)&ylo[px * 64 + chunk * 8];

        bfrag whi0 = *(const bfrag*)((const char*)g_whi + woffb + s * 32);
        bfrag whi1 = *(const bfrag*)((const char*)g_whi + woffb + s * 32 + 4096);
        bfrag wlo0 = *(const bfrag*)((const char*)g_wlo + woffb + s * 32);
        bfrag wlo1 = *(const bfrag*)((const char*)g_wlo + woffb + s * 32 + 4096);

        acc0 = __builtin_amdgcn_mfma_f32_32x32x16_bf16(whi0, yh, acc0, 0, 0, 0);
        acc0 = __builtin_amdgcn_mfma_f32_32x32x16_bf16(whi0, yl, acc0, 0, 0, 0);
        acc0 = __builtin_amdgcn_mfma_f32_32x32x16_bf16(wlo0, yh, acc0, 0, 0, 0);
        acc1 = __builtin_amdgcn_mfma_f32_32x32x16_bf16(whi1, yh, acc1, 0, 0, 0);
        acc1 = __builtin_amdgcn_mfma_f32_32x32x16_bf16(whi1, yl, acc1, 0, 0, 0);
        acc1 = __builtin_amdgcn_mfma_f32_32x32x16_bf16(wlo1, yh, acc1, 0, 0, 0);
    }

    // epilogue: D layout col=lane&31, row=(reg&3)+8*(reg>>2)+4*(lane>>5)  [verified R4/R5]
    float* ob = out + ((size_t)b << 20) + gy * HW + px;
    #pragma unroll
    for (int q = 0; q < 4; ++q) {
        const int obase = 8 * q + 4 * g;
        float4 b0 = *(const float4*)&conv_b[obase];
        float4 b1 = *(const float4*)&conv_b[32 + obase];
        const float* b0f = (const float*)&b0;
        const float* b1f = (const float*)&b1;
        #pragma unroll
        for (int rr = 0; rr < 4; ++rr) {
            ob[(size_t)(obase + rr) * 16384]      = acc0[q * 4 + rr] + b0f[rr];
            ob[(size_t)(32 + obase + rr) * 16384] = acc1[q * 4 + rr] + b1f[rr];
        }
    }
}

extern "C" void kernel_launch(void* const* d_in, const int* in_sizes, int n_in,
                              void* d_out, int out_size, void* d_ws, size_t ws_size,
                              hipStream_t stream) {
    const float* x0     = (const float*)d_in[0];
    const float* v      = (const float*)d_in[1];
    const float* ca_w1  = (const float*)d_in[2];
    const float* ca_w2  = (const float*)d_in[3];
    const float* k_w1   = (const float*)d_in[4];
    const float* k_w2   = (const float*)d_in[5];
    const float* conv_w = (const float*)d_in[6];
    const float* conv_b = (const float*)d_in[7];
    float* outp = (float*)d_out;

    dgfem_prep<<<dim3(33), dim3(64), 0, stream>>>(v, ca_w1, ca_w2, k_w1, k_w2, conv_w);
    dgfem_main<<<dim3(4096), dim3(256), 0, stream>>>(x0, conv_b, outp);
}

// Round 7
// 146.816 us; speedup vs baseline: 2.1147x; 2.1147x over previous
//
#include <hip/hip_runtime.h>

#define HW 128

typedef __attribute__((ext_vector_type(8))) short  bfrag;   // 8 bf16 (4 VGPRs)
typedef __attribute__((ext_vector_type(16))) float f16x;    // 32x32 accumulator

__device__ __forceinline__ float lrelu(float x) { return x > 0.f ? x : 0.1f * x; }

// RNE fp32 -> bf16 (prep only)
__device__ __forceinline__ short f2bf(float f) {
    unsigned u = __builtin_bit_cast(unsigned, f);
    u = u + 0x7FFFu + ((u >> 16) & 1u);
    return (short)(u >> 16);
}
__device__ __forceinline__ float bf2f(short s) {
    return __builtin_bit_cast(float, (unsigned)(unsigned short)s << 16);
}

// [b][(s*8+j)*20 + tap*2 + g] : att-folded depthwise taps, half-wave-paired
__device__ float g_kpair[32 * 640];
__device__ short g_whi[4096], g_wlo[4096];        // conv_w bf16 hi/lo, [o*64+c]

// ---------- prep: b<32 -> att-folded kernels (paired layout); b==32 -> W split ----------
__global__ __launch_bounds__(64) void dgfem_prep(
    const float* __restrict__ v, const float* __restrict__ ca_w1,
    const float* __restrict__ ca_w2, const float* __restrict__ k_w1,
    const float* __restrict__ k_w2, const float* __restrict__ conv_w)
{
    const int b = blockIdx.x;
    const int t = threadIdx.x;           // 64 threads

    if (b == 32) {                       // bf16 hi/lo decomposition of conv_w
        for (int i = t; i < 4096; i += 64) {
            float wv = conv_w[i];
            short hi = f2bf(wv);
            short lo = f2bf(wv - bf2f(hi));
            g_whi[i] = hi;
            g_wlo[i] = lo;
        }
        return;
    }

    __shared__ float vb[64], t1[8], att[64], t2[64];
    vb[t] = v[b * 64 + t];
    __syncthreads();

    if (t < 8) {
        float s = 0.f;
        for (int j = 0; j < 64; ++j) s += vb[j] * ca_w1[t * 64 + j];
        t1[t] = lrelu(s);
    }
    {
        float s = 0.f;
        for (int j = 0; j < 64; ++j) s += vb[j] * k_w1[t * 64 + j];
        t2[t] = lrelu(s);
    }
    __syncthreads();
    {
        float s = 0.f;
        for (int i = 0; i < 8; ++i) s += t1[i] * ca_w2[t * 8 + i];
        att[t] = 1.f / (1.f + expf(-s));
    }
    __syncthreads();
    // fold att[c] into kernel (conv(x*a,k) == conv(x,a*k)); paired layout
    for (int r = t; r < 576; r += 64) {
        int c = r / 9, tp = r - c * 9;
        float s = 0.f;
        for (int j = 0; j < 64; ++j) s += t2[j] * k_w2[r * 64 + j];
        int ss = c >> 4, gg = (c >> 3) & 1, jj = c & 7;
        g_kpair[b * 640 + (ss * 8 + jj) * 20 + tp * 2 + gg] = s * att[c];
    }
}

// ---- fused: depthwise 3x3 (batched direct loads) + 1x1 via bf16-split MFMA ----
__global__ __launch_bounds__(256)
__attribute__((amdgpu_waves_per_eu(3, 3)))
void dgfem_main(
    const float* __restrict__ x0, const float* __restrict__ conv_b,
    float* __restrict__ out)
{
    const int t  = threadIdx.x;
    const int w  = t >> 6;               // wave = px col-tile (0..3)
    const int l  = t & 63;
    const int g  = l >> 5;               // k-half of the wave
    const int ln = l & 31;               // col / A-row within 32x32 tile

    // XCD-aware swizzle: XCD k gets contiguous rows of batches 4k..4k+3
    const int bid  = blockIdx.x;                 // 0..4095
    const int orig = (bid & 7) * 512 + (bid >> 3);
    const int b    = orig >> 7;                  // 0..31
    const int gy   = orig & 127;                 // output row
    const int px   = w * 32 + ln;                // 0..127

    __shared__ float kls[640];                   // this b's paired kernel table
    for (int i = t; i < 640; i += 256) kls[i] = g_kpair[b * 640 + i];

    // per-lane BYTE offsets (incl. g-part: g*8 channels = 524288 B) + masks
    int   offb[9];
    float mskf[9];
    #pragma unroll
    for (int dy = 0; dy < 3; ++dy) {
        int yi = gy + dy - 1;
        bool my = (unsigned)yi < HW;
        int cy = my ? yi : 0;
        #pragma unroll
        for (int dx = 0; dx < 3; ++dx) {
            int xi = px + dx - 1;
            bool mx = (unsigned)xi < HW;
            int cx = mx ? xi : 0;
            offb[dy * 3 + dx] = (g * 131072 + cy * HW + cx) * 4;
            mskf[dy * 3 + dx] = (my && mx) ? 1.f : 0.f;
        }
    }
    const int woffb = ln * 128 + g * 16;         // W-row byte offset (o-tile 0)

    const char* xb  = (const char*)(x0 + ((size_t)b << 20));
    const char* klb = (const char*)kls + g * 4;
    __syncthreads();

    f16x acc0, acc1;
    #pragma unroll
    for (int i = 0; i < 16; ++i) { acc0[i] = 0.f; acc1[i] = 0.f; }

    #pragma unroll 1
    for (int s = 0; s < 4; ++s) {
        bfrag yhi, ylo;
        const char* xs_ = xb + (size_t)s * (16 * 65536);
        const char* ks_ = klb + s * 640;         // (s*8)*20*4

        #pragma unroll
        for (int jh = 0; jh < 2; ++jh) {
            // ---- batch-issue 36 x-loads (4 channels x 9 taps) ----
            float xv[4][9];
            #pragma unroll
            for (int j4 = 0; j4 < 4; ++j4) {
                const char* xc = xs_ + (jh * 4 + j4) * 65536;
                #pragma unroll
                for (int tp = 0; tp < 9; ++tp)
                    xv[j4][tp] = *(const float*)(xc + offb[tp]);
            }
            // ---- consume: 4 independent 9-FMA chains ----
            #pragma unroll
            for (int j4 = 0; j4 < 4; ++j4) {
                const int j = jh * 4 + j4;
                const char* kc = ks_ + j * 80;
                float a = 0.f;
                #pragma unroll
                for (int tp = 0; tp < 9; ++tp) {
                    float kv = *(const float*)(kc + tp * 8);   // ds_read imm offset
                    a = fmaf(kv, mskf[tp] * xv[j4][tp], a);
                }
                a = lrelu(a);
                // truncation-based hi/lo split (exact residual)
                unsigned u  = __builtin_bit_cast(unsigned, a);
                float   hif = __builtin_bit_cast(float, u & 0xFFFF0000u);
                float   lof = a - hif;
                yhi[j] = (short)(u >> 16);
                ylo[j] = (short)(__builtin_bit_cast(unsigned, lof) >> 16);
            }
        }

        // W fragments: per-lane voffset + scalar s*32 imm
        const char* whb = (const char*)g_whi + woffb + s * 32;
        const char* wlb = (const char*)g_wlo + woffb + s * 32;
        bfrag whi0 = *(const bfrag*)(whb);
        bfrag whi1 = *(const bfrag*)(whb + 4096);
        bfrag wlo0 = *(const bfrag*)(wlb);
        bfrag wlo1 = *(const bfrag*)(wlb + 4096);

        acc0 = __builtin_amdgcn_mfma_f32_32x32x16_bf16(whi0, yhi, acc0, 0, 0, 0);
        acc0 = __builtin_amdgcn_mfma_f32_32x32x16_bf16(whi0, ylo, acc0, 0, 0, 0);
        acc0 = __builtin_amdgcn_mfma_f32_32x32x16_bf16(wlo0, yhi, acc0, 0, 0, 0);
        acc1 = __builtin_amdgcn_mfma_f32_32x32x16_bf16(whi1, yhi, acc1, 0, 0, 0);
        acc1 = __builtin_amdgcn_mfma_f32_32x32x16_bf16(whi1, ylo, acc1, 0, 0, 0);
        acc1 = __builtin_amdgcn_mfma_f32_32x32x16_bf16(wlo1, yhi, acc1, 0, 0, 0);
    }

    // epilogue: D layout col=lane&31, row=(reg&3)+8*(reg>>2)+4*(lane>>5)  [verified R4/R5]
    float* ob = out + ((size_t)b << 20) + gy * HW + px;
    #pragma unroll
    for (int q = 0; q < 4; ++q) {
        const int obase = 8 * q + 4 * g;
        float4 b0 = *(const float4*)&conv_b[obase];
        float4 b1 = *(const float4*)&conv_b[32 + obase];
        const float* b0f = (const float*)&b0;
        const float* b1f = (const float*)&b1;
        #pragma unroll
        for (int rr = 0; rr < 4; ++rr) {
            ob[(size_t)(obase + rr) * 16384]      = acc0[q * 4 + rr] + b0f[rr];
            ob[(size_t)(32 + obase + rr) * 16384] = acc1[q * 4 + rr] + b1f[rr];
        }
    }
}

extern "C" void kernel_launch(void* const* d_in, const int* in_sizes, int n_in,
                              void* d_out, int out_size, void* d_ws, size_t ws_size,
                              hipStream_t stream) {
    const float* x0     = (const float*)d_in[0];
    const float* v      = (const float*)d_in[1];
    const float* ca_w1  = (const float*)d_in[2];
    const float* ca_w2  = (const float*)d_in[3];
    const float* k_w1   = (const float*)d_in[4];
    const float* k_w2   = (const float*)d_in[5];
    const float* conv_w = (const float*)d_in[6];
    const float* conv_b = (const float*)d_in[7];
    float* outp = (float*)d_out;

    dgfem_prep<<<dim3(33), dim3(64), 0, stream>>>(v, ca_w1, ca_w2, k_w1, k_w2, conv_w);
    dgfem_main<<<dim3(4096), dim3(256), 0, stream>>>(x0, conv_b, outp);
}

// Round 8
// 123.299 us; speedup vs baseline: 2.5180x; 1.1907x over previous
//
#include <hip/hip_runtime.h>

#define HW 128
#define TW 32
#define TH 8

typedef __attribute__((ext_vector_type(2))) float f32x2;

__device__ __forceinline__ float lrelu(float x) { return x > 0.f ? x : 0.1f * x; }

// Static device scratch
__device__ float g_kern[32 * 64 * 9];   // att-folded depthwise kernels
__device__ float g_wT[64 * 64];         // g_wT[c*64+o] = conv_w[o*64+c]

// ---------------- prep: b<32 -> att-scaled kernels; b==32 -> W transpose ----------------
__global__ __launch_bounds__(64) void dgfem_prep(
    const float* __restrict__ v, const float* __restrict__ ca_w1,
    const float* __restrict__ ca_w2, const float* __restrict__ k_w1,
    const float* __restrict__ k_w2, const float* __restrict__ conv_w)
{
    const int b = blockIdx.x;
    const int t = threadIdx.x;           // 64 threads

    if (b == 32) {                       // transpose conv_w -> c-major rows
        for (int i = t; i < 4096; i += 64)
            g_wT[(i & 63) * 64 + (i >> 6)] = conv_w[i];
        return;
    }

    __shared__ float vb[64], t1[8], att[64], t2[64];
    vb[t] = v[b * 64 + t];
    __syncthreads();

    if (t < 8) {
        float s = 0.f;
        for (int j = 0; j < 64; ++j) s += vb[j] * ca_w1[t * 64 + j];
        t1[t] = lrelu(s);
    }
    {
        float s = 0.f;
        for (int j = 0; j < 64; ++j) s += vb[j] * k_w1[t * 64 + j];
        t2[t] = lrelu(s);
    }
    __syncthreads();
    {
        float s = 0.f;
        for (int i = 0; i < 8; ++i) s += t1[i] * ca_w2[t * 8 + i];
        att[t] = 1.f / (1.f + expf(-s));
    }
    __syncthreads();
    // fold att[c] into the kernel: conv(x*a, k) == conv(x, a*k)
    for (int r = t; r < 576; r += 64) {
        float s = 0.f;
        for (int j = 0; j < 64; ++j) s += t2[j] * k_w2[r * 64 + j];
        g_kern[b * 576 + r] = s * att[r / 9];
    }
}

// ---- fused: depthwise 3x3 (direct global/L1) + lrelu + 1x1 via packed-f32 FMA ----
__global__ __launch_bounds__(256) void dgfem_main(
    const float* __restrict__ x0, const float* __restrict__ conv_b,
    float* __restrict__ out)
{
    const int t  = threadIdx.x;          // 256 = 32x8 pixel tile, 1 px/thread
    const int b  = blockIdx.z;
    const int gx = blockIdx.x * TW + (t & (TW - 1));
    const int gy = blockIdx.y * TH + (t >> 5);

    // per-thread stencil geometry: 9 offsets + 9 masks (channel-invariant)
    int  off[9];
    bool msk[9];
    #pragma unroll
    for (int dy = 0; dy < 3; ++dy)
        #pragma unroll
        for (int dx = 0; dx < 3; ++dx) {
            int xi = gx + dx - 1, yi = gy + dy - 1;
            bool in = ((unsigned)xi < HW) && ((unsigned)yi < HW);
            off[dy * 3 + dx] = in ? (yi * HW + xi) : 0;
            msk[dy * 3 + dx] = in;
        }

    const size_t bbase = (size_t)b * 64 * (HW * HW);
    const float* xb = x0 + bbase;
    const float* kb = g_kern + b * 576;

    f32x2 acc2[32];
    #pragma unroll
    for (int o = 0; o < 32; ++o) acc2[o] = (f32x2){0.f, 0.f};

    #pragma unroll 2
    for (int c = 0; c < 64; ++c) {
        const float* xc = xb + c * (HW * HW);   // divergent offsets, uniform base
        const float* kc = kb + c * 9;           // uniform -> s_load
        const f32x2* wc2 = (const f32x2*)(g_wT + c * 64);  // uniform -> s_load pairs

        float xv[9];
        #pragma unroll
        for (int tp = 0; tp < 9; ++tp) xv[tp] = xc[off[tp]];

        float yv = 0.f;
        #pragma unroll
        for (int tp = 0; tp < 9; ++tp) {
            float xm = msk[tp] ? xv[tp] : 0.f;  // zero-pad boundary
            yv += kc[tp] * xm;
        }
        yv = lrelu(yv);

        const f32x2 ysp = (f32x2){yv, yv};
        #pragma unroll
        for (int o2 = 0; o2 < 32; ++o2)         // v_pk_fma_f32: 2 outputs / instr
            acc2[o2] = __builtin_elementwise_fma(wc2[o2], ysp, acc2[o2]);
    }

    float* op = out + bbase + (size_t)(gy * HW + gx);
    #pragma unroll
    for (int o2 = 0; o2 < 32; ++o2) {
        op[(size_t)(2 * o2)     * (HW * HW)] = acc2[o2].x + conv_b[2 * o2];
        op[(size_t)(2 * o2 + 1) * (HW * HW)] = acc2[o2].y + conv_b[2 * o2 + 1];
    }
}

extern "C" void kernel_launch(void* const* d_in, const int* in_sizes, int n_in,
                              void* d_out, int out_size, void* d_ws, size_t ws_size,
                              hipStream_t stream) {
    const float* x0     = (const float*)d_in[0];
    const float* v      = (const float*)d_in[1];
    const float* ca_w1  = (const float*)d_in[2];
    const float* ca_w2  = (const float*)d_in[3];
    const float* k_w1   = (const float*)d_in[4];
    const float* k_w2   = (const float*)d_in[5];
    const float* conv_w = (const float*)d_in[6];
    const float* conv_b = (const float*)d_in[7];
    float* outp = (float*)d_out;

    dgfem_prep<<<dim3(33), dim3(64), 0, stream>>>(v, ca_w1, ca_w2, k_w1, k_w2, conv_w);
    dgfem_main<<<dim3(HW / TW, HW / TH, 32), dim3(256), 0, stream>>>(x0, conv_b, outp);
}